// Round 16
// baseline (662.236 us; speedup 1.0000x reference)
//
#include <hip/hip_runtime.h>
#include <stdint.h>

#define BATCH 512
#define SEQ   512
#define HID   128
#define BT    16        // batch tile per block
#define ROWB  528       // LDS act row stride in bytes
#define NTILE 32        // BATCH/BT
#define CH    8         // steps per done-chunk (back-pressure only)
#define RING  64        // ring slots (steps) per layer boundary
#define FPAD  32        // ints per flag (128B line)
#define SKEW  8         // startup lag consumers establish vs producer

typedef _Float16 half8 __attribute__((ext_vector_type(8)));
typedef __fp16   fp16x2 __attribute__((ext_vector_type(2)));
typedef float f32x4 __attribute__((ext_vector_type(4)));
typedef unsigned long long u64;

// In-loop barrier without vmcnt drain: only LDS handoff must be visible.
#define BARRIER_LDS() do { \
    asm volatile("s_waitcnt lgkmcnt(0)" ::: "memory"); \
    __builtin_amdgcn_s_barrier(); \
  } while(0)

union UHP { uint32_t u; _Float16 h[2]; };
union UH2V { fp16x2 h; uint32_t u; };

// RNE pack (weights/bias one-time conversion)
__device__ __forceinline__ uint32_t pack2f(float a, float b){
  UHP r; r.h[0] = (_Float16)a; r.h[1] = (_Float16)b; return r.u;
}
// Fast packed cvt (1 inst) for per-step activation packing
__device__ __forceinline__ uint32_t pkrtz(float a, float b){
#if __has_builtin(__builtin_amdgcn_cvt_pkrtz)
  UH2V r; r.h = __builtin_amdgcn_cvt_pkrtz(a, b); return r.u;
#else
  return pack2f(a, b);
#endif
}
__device__ __forceinline__ float unpk(uint32_t u, int i){
  UHP r; r.u = u; return (float)r.h[i];
}

__device__ __forceinline__ float rcp_(float x){
#if __has_builtin(__builtin_amdgcn_rcpf)
  return __builtin_amdgcn_rcpf(x);
#else
  return 1.f / x;
#endif
}
__device__ __forceinline__ float exp2_(float x){
#if __has_builtin(__builtin_amdgcn_exp2f)
  return __builtin_amdgcn_exp2f(x);
#else
  return exp2f(x);
#endif
}
__device__ __forceinline__ float sigm(float x){ return rcp_(1.f + exp2_(x * -1.44269504f)); }
__device__ __forceinline__ float tanh_(float x){ return 1.f - 2.f * rcp_(exp2_(x * 2.88539008f) + 1.f); }

__device__ __forceinline__ int aload(const int* p){
  return __hip_atomic_load(p, __ATOMIC_RELAXED, __HIP_MEMORY_SCOPE_AGENT);
}

// MODE 0: x fp32 -> ring0 ; MODE 1: ring0 -> ring1 ; MODE 2: ring1 -> y fp32
//
// Round-16 = round-15 (VALU diet: strength-reduced bumped pointers for all
// per-step global addresses + 1-inst packed f32->f16 cvt), with the
// cvt_pkrtz return-type fixed (__fp16 vector, not _Float16 vector).
template<int MODE>
__device__ __forceinline__ void run_layer(
    const float* __restrict__ Wih, const float* __restrict__ Whh,
    const float* __restrict__ bih, const float* __restrict__ bhh,
    const float* __restrict__ x, uint32_t* __restrict__ rin,
    uint32_t* __restrict__ rout, float* __restrict__ y,
    int* src_ready, int* src_done, int* dst_ready, int* dst_done,
    int b0, char* act0, char* act1)
{
  const int tid  = threadIdx.x;
  const int lane = tid & 63;
  const int w    = tid >> 6;
  const int u0   = w * 16;
  const int rm   = lane & 15;   // batch col within tile
  const int kq   = lane >> 4;   // k-quarter / acc row group

  // ---- weights -> f16 register fragments (fused K=256: s<4 Wih, s>=4 Whh)
  half8 wf[4][8];
  #pragma unroll
  for (int g = 0; g < 4; ++g){
    const int grow = g * HID + u0 + rm;
    #pragma unroll
    for (int s = 0; s < 8; ++s){
      const int k = s * 32 + kq * 8;
      const float* src = (s < 4) ? (Wih + (size_t)grow * HID + k)
                                 : (Whh + (size_t)grow * HID + (k - HID));
      const float4 aa = *(const float4*)src;
      const float4 bb = *(const float4*)(src + 4);
      half8 hh;
      hh[0]=(_Float16)aa.x; hh[1]=(_Float16)aa.y; hh[2]=(_Float16)aa.z; hh[3]=(_Float16)aa.w;
      hh[4]=(_Float16)bb.x; hh[5]=(_Float16)bb.y; hh[6]=(_Float16)bb.z; hh[7]=(_Float16)bb.w;
      wf[g][s] = hh;
    }
  }
  f32x4 bias4[4];
  #pragma unroll
  for (int g = 0; g < 4; ++g)
    #pragma unroll
    for (int r = 0; r < 4; ++r){
      const int row = g * HID + u0 + kq * 4 + r;
      bias4[g][r] = bih[row] + bhh[row];
    }

  // ---- staging thread mapping: 16 rows x 128 f16
  const int sb = tid >> 5;   // 0..15 batch row
  const int sk = tid & 31;   // col group (8B)

  auto raddr = [&](int t){
    return (const u64*)(rin + ((size_t)(t & (RING-1)) * BATCH + b0 + sb) * 64 + sk * 2);
  };

  float4 pfa, pfb;         // MODE 0: x prefetch (cur / nxt)
  u64    pga = 0, pgb = 0; // MODE 1/2: ring prefetch

  // ---- strength-reduced pointers (round-15 change)
  const float4* xpp = nullptr;  // MODE 0: x(t+2) prefetch
  const u64*    ripp = nullptr; // MODE 1/2: ring-in slot t+2 prefetch
  uint32_t*     rop = nullptr;  // MODE 0/1: ring-out slot t-1 store
  float*        yp  = nullptr;  // MODE 2: y row t-1 store

  int fseen = 0, fpend = 0, dseen = 0;

  // ---- prologue: SKEW lag, stage data(0) -> act0, preload data(1)
  if constexpr (MODE != 0){
    fseen = aload(src_ready);
    while (fseen < SKEW){ __builtin_amdgcn_s_sleep(8); fseen = aload(src_ready); }
  }
  if constexpr (MODE == 0){
    const float4* xa0 = (const float4*)(x + (size_t)(b0 + sb) * SEQ * HID + sk * 4);
    const float4 v = xa0[0];
    uint2 p; p.x = pkrtz(v.x, v.y); p.y = pkrtz(v.z, v.w);
    *(uint2*)(act0 + sb * ROWB + sk * 8) = p;
    pfa = *(const float4*)((const float*)xa0 + HID);
    xpp = (const float4*)((const float*)xa0 + 2 * HID);
  } else {
    const u64 v = __hip_atomic_load(raddr(0), __ATOMIC_RELAXED, __HIP_MEMORY_SCOPE_AGENT);
    *(u64*)(act0 + sb * ROWB + sk * 8) = v;
    pga = __hip_atomic_load(raddr(1), __ATOMIC_RELAXED, __HIP_MEMORY_SCOPE_AGENT);
    ripp = raddr(2);
    fpend = aload(src_ready);
  }
  if constexpr (MODE != 2)
    rop = rout + ((size_t)b0 + rm) * 64 + (u0 >> 1) + kq * 2;   // slot 0
  else
    yp = y + ((size_t)u0 + kq * 4) * BATCH + b0 + rm;           // row 0
  if (tid < 256)
    *(uint4*)(act0 + (tid >> 4) * ROWB + 256 + (tid & 15) * 16) = make_uint4(0u,0u,0u,0u);
  __syncthreads();   // prologue: full drain once

  f32x4 c4 = {0.f, 0.f, 0.f, 0.f};
  const int boff = rm * ROWB + kq * 16;
  int cur = 0;

  uint2 hp = {0u, 0u};     // deferred-store state (h of step t-1, f16 packed)

  for (int t = 0; t < SEQ; ++t){
    char* bc = cur ? act1 : act0;
    char* bn = cur ? act0 : act1;
    const int tn   = t + 1;
    const int tpre = t + 2;

    // ---- PHASE 1: all VMEM issue (latency hides under MFMA phase) ----
    if (t > 0){
      if constexpr (MODE != 2){
        const u64 hp64 = ((u64)hp.y << 32) | (u64)hp.x;
        __hip_atomic_store((u64*)rop, hp64, __ATOMIC_RELAXED, __HIP_MEMORY_SCOPE_AGENT);
        rop += BATCH * 64;
        if ((t & (RING-1)) == 0) rop -= (size_t)RING * BATCH * 64;
      } else {
        yp[0]         = unpk(hp.x, 0);
        yp[BATCH]     = unpk(hp.x, 1);
        yp[2 * BATCH] = unpk(hp.y, 0);
        yp[3 * BATCH] = unpk(hp.y, 1);
        yp += (size_t)HID * BATCH;
      }
    }
    // continuous ready publish: value t-2 (stores issued >=1.5 steps ago)
    if (tid == 0){
      if constexpr (MODE != 2){
        if (t >= 3)
          __hip_atomic_store(dst_ready, t - 2, __ATOMIC_RELAXED, __HIP_MEMORY_SCOPE_AGENT);
      }
      if constexpr (MODE != 0){
        if ((t & (CH-1)) == 0 && t > 0)
          __hip_atomic_store(src_done, t >> 3, __ATOMIC_RELAXED, __HIP_MEMORY_SCOPE_AGENT);
      }
    }
    // back-pressure: cached; blocking refresh only if bound violated
    if constexpr (MODE != 2){
      if ((t & (CH-1)) == 0 && t >= RING){
        const int need = (t >> 3) - 7;
        if (dseen < need){
          dseen = aload(dst_done);
          while (dseen < need){ __builtin_amdgcn_s_sleep(8); dseen = aload(dst_done); }
        }
      }
    }
    // pipelined flag check + 2-deep prefetch issue (slot t+2)
    if constexpr (MODE != 0){
      if (fpend > fseen) fseen = fpend;
      fpend = aload(src_ready);
      if (tpre < SEQ && fseen < tpre + 1){
        fseen = aload(src_ready);
        while (fseen < tpre + 1){ __builtin_amdgcn_s_sleep(2); fseen = aload(src_ready); }
      }
    }
    if (tpre < SEQ){
      if constexpr (MODE == 0){
        pfb = *xpp;
        xpp = (const float4*)((const float*)xpp + HID);
      } else {
        pgb = __hip_atomic_load(ripp, __ATOMIC_RELAXED, __HIP_MEMORY_SCOPE_AGENT);
        ripp += (size_t)BATCH * 32;   // BATCH*64 uint32 = BATCH*32 u64
        if (((t + 3) & (RING-1)) == 0) ripp -= (size_t)RING * BATCH * 32;
      }
    }

    // ---- PHASE 2: fused gate GEMM (K=256), acc init = bias ----
    __builtin_amdgcn_s_setprio(1);
    f32x4 a0 = bias4[0], a1 = bias4[1], a2 = bias4[2], a3 = bias4[3];
    #pragma unroll
    for (int s = 0; s < 8; ++s){
      const half8 bf = *(const half8*)(bc + boff + s * 64);
      a0 = __builtin_amdgcn_mfma_f32_16x16x32_f16(wf[0][s], bf, a0, 0, 0, 0);
      a1 = __builtin_amdgcn_mfma_f32_16x16x32_f16(wf[1][s], bf, a1, 0, 0, 0);
      a2 = __builtin_amdgcn_mfma_f32_16x16x32_f16(wf[2][s], bf, a2, 0, 0, 0);
      a3 = __builtin_amdgcn_mfma_f32_16x16x32_f16(wf[3][s], bf, a3, 0, 0, 0);
    }

    // ---- PHASE 3: x(t+1) staging -> bn (LDS pipe idle during trans burst)
    if (tn < SEQ){
      if constexpr (MODE == 0){
        uint2 p; p.x = pkrtz(pfa.x, pfa.y); p.y = pkrtz(pfa.z, pfa.w);
        *(uint2*)(bn + sb * ROWB + sk * 8) = p;
      } else {
        *(u64*)(bn + sb * ROWB + sk * 8) = pga;
      }
    }

    // ---- PHASE 4: elementwise (trans burst), lane holds i,f,g,o x 4 units
    float hvr[4];
    #pragma unroll
    for (int r = 0; r < 4; ++r){
      const float ii = sigm(a0[r]), ff = sigm(a1[r]);
      const float gg = tanh_(a2[r]), oo = sigm(a3[r]);
      c4[r] = ff * c4[r] + ii * gg;
      hvr[r] = oo * tanh_(c4[r]);
    }
    __builtin_amdgcn_s_setprio(0);
    hp.x = pkrtz(hvr[0], hvr[1]);
    hp.y = pkrtz(hvr[2], hvr[3]);

    // ---- PHASE 5: h(t) -> bn (next step's critical input) ----
    *(uint2*)(bn + rm * ROWB + 256 + u0 * 2 + kq * 8) = hp;

    BARRIER_LDS();
    pfa = pfb; pga = pgb;
    cur ^= 1;
  }

  // ---- tail: flush step SEQ-1, full drain, final publishes
  if constexpr (MODE != 2){
    const u64 hp64 = ((u64)hp.y << 32) | (u64)hp.x;
    __hip_atomic_store((u64*)rop, hp64, __ATOMIC_RELAXED, __HIP_MEMORY_SCOPE_AGENT);
  } else {
    yp[0]         = unpk(hp.x, 0);
    yp[BATCH]     = unpk(hp.x, 1);
    yp[2 * BATCH] = unpk(hp.y, 0);
    yp[3 * BATCH] = unpk(hp.y, 1);
  }
  __syncthreads();   // tail: FULL drain -> final flags valid
  if (tid == 0){
    if constexpr (MODE != 2)
      __hip_atomic_store(dst_ready, SEQ, __ATOMIC_RELAXED, __HIP_MEMORY_SCOPE_AGENT);
    if constexpr (MODE != 0)
      __hip_atomic_store(src_done, SEQ / CH, __ATOMIC_RELAXED, __HIP_MEMORY_SCOPE_AGENT);
  }
}

// Grid: 96 blocks (3 layers x 32 tiles) x 512 threads, (512,2): the proven
// codegen shape. Allocator facts (this session): 512-thr kernels pin at 128
// VGPR ((512,2)==(512,1)), 1024-thr at 64 — exceeding either spills.
__global__ __launch_bounds__(512, 2) void lstm_pipe(
    const float* W0i, const float* W0h, const float* b0i, const float* b0h,
    const float* W1i, const float* W1h, const float* b1i, const float* b1h,
    const float* W2i, const float* W2h, const float* b2i, const float* b2h,
    const float* x, float* y, uint32_t* ring, int* flags)
{
  const int layer = blockIdx.x >> 5;   // 0,1,2
  const int tile  = blockIdx.x & 31;
  const int b0    = tile * BT;

  __shared__ char act[2][BT * ROWB];

  uint32_t* r0 = ring;                                 // boundary 0: L0 -> L1
  uint32_t* r1 = ring + (size_t)RING * BATCH * 64;     // boundary 1: L1 -> L2

  int* p0 = flags + (0 * NTILE + tile) * FPAD;   // ready, boundary 0
  int* p1 = flags + (1 * NTILE + tile) * FPAD;   // ready, boundary 1
  int* c0 = flags + (2 * NTILE + tile) * FPAD;   // done,  boundary 0
  int* c1 = flags + (3 * NTILE + tile) * FPAD;   // done,  boundary 1

  if (layer == 0){
    run_layer<0>(W0i, W0h, b0i, b0h, x, nullptr, r0, nullptr,
                 nullptr, nullptr, p0, c0, b0, act[0], act[1]);
  } else if (layer == 1){
    run_layer<1>(W1i, W1h, b1i, b1h, nullptr, r0, r1, nullptr,
                 p0, c0, p1, c1, b0, act[0], act[1]);
  } else {
    run_layer<2>(W2i, W2h, b2i, b2h, nullptr, r1, nullptr, y,
                 p1, c1, nullptr, nullptr, b0, act[0], act[1]);
  }
}

extern "C" void kernel_launch(void* const* d_in, const int* in_sizes, int n_in,
                              void* d_out, int out_size, void* d_ws, size_t ws_size,
                              hipStream_t stream) {
  const float* x    = (const float*)d_in[0];
  const float* Wih0 = (const float*)d_in[1];
  const float* Whh0 = (const float*)d_in[2];
  const float* bih0 = (const float*)d_in[3];
  const float* bhh0 = (const float*)d_in[4];
  const float* Wih1 = (const float*)d_in[5];
  const float* Whh1 = (const float*)d_in[6];
  const float* bih1 = (const float*)d_in[7];
  const float* bhh1 = (const float*)d_in[8];
  const float* Wih2 = (const float*)d_in[9];
  const float* Whh2 = (const float*)d_in[10];
  const float* bih2 = (const float*)d_in[11];
  const float* bhh2 = (const float*)d_in[12];

  float* out = (float*)d_out;
  uint32_t* ring = (uint32_t*)d_ws;
  const size_t ring_bytes = (size_t)2 * RING * BATCH * 64 * 4;   // 16 MiB
  int* flags = (int*)((char*)d_ws + ring_bytes);

  (void)hipMemsetAsync(flags, 0, 4 * NTILE * FPAD * sizeof(int), stream);

  dim3 grid(3 * NTILE), block(512);
  lstm_pipe<<<grid, block, 0, stream>>>(
      Wih0, Whh0, bih0, bhh0, Wih1, Whh1, bih1, bhh1, Wih2, Whh2, bih2, bhh2,
      x, out, ring, flags);
}